// Round 1
// baseline (222.322 us; speedup 1.0000x reference)
//
#include <hip/hip_runtime.h>
#include <hip/hip_bf16.h>
#include <math.h>

// Problem constants (B,F,H,E,O) = (512,512,512,8,512)
enum { Bq = 512, Fq = 512, Hq = 512, Eq = 8, Oq = 512 };

typedef __attribute__((ext_vector_type(8))) short short8;
typedef __attribute__((ext_vector_type(4))) float floatx4;

static __device__ __forceinline__ unsigned short f2bf(float f) {
  unsigned u = __float_as_uint(f);
  u += 0x7fffu + ((u >> 16) & 1u);
  return (unsigned short)(u >> 16);
}
static __device__ __forceinline__ float bf2f(unsigned short h) {
  return __uint_as_float(((unsigned)h) << 16);
}
static __device__ __forceinline__ float elu1(float v) {
  return v > 0.f ? v : (__expf(v) - 1.f);
}

// ---------------- fp32 -> bf16 convert, 3 equal-size segments ----------------
__global__ __launch_bounds__(256) void cvt3_kernel(
    const float* __restrict__ s0, const float* __restrict__ s1,
    const float* __restrict__ s2, unsigned short* __restrict__ d0,
    unsigned short* __restrict__ d1, unsigned short* __restrict__ d2,
    int nvec /* float4 count per segment */) {
  int i = blockIdx.x * 256 + threadIdx.x;
  if (i >= 3 * nvec) return;
  int seg = i / nvec;
  int j = i - seg * nvec;
  const float4* s = (seg == 0) ? (const float4*)s0
                  : (seg == 1) ? (const float4*)s1 : (const float4*)s2;
  unsigned short* d = (seg == 0) ? d0 : (seg == 1) ? d1 : d2;
  float4 v = s[j];
  ushort4 o;
  o.x = f2bf(v.x); o.y = f2bf(v.y); o.z = f2bf(v.z); o.w = f2bf(v.w);
  *(ushort4*)(d + 4 * (size_t)j) = o;
}

// ---------------- bf16 MFMA GEMM: C[M,N] = A[M,K] @ W[N,K]^T ----------------
// Both A and W row-major, K contiguous (torch-Linear layout).
// Block = 256 threads = 4 waves in 2x2; wave tile = (BM/2)x(BN/2) of 16x16 MFMA tiles.
// EPI==0: store fp32 to Cf.  EPI==1: +bias, ELU, store bf16 to Cb.
template <int BM, int BN, int BK, int TM, int TN, int EPI>
__global__ __launch_bounds__(256) void gemm_bt(
    const unsigned short* __restrict__ A, const unsigned short* __restrict__ W,
    const float* __restrict__ bias, float* __restrict__ Cf,
    unsigned short* __restrict__ Cb, int M, int N, int K) {
  __shared__ unsigned short As[BM * BK];
  __shared__ unsigned short Bs[BN * BK];
  const int tid = threadIdx.x;
  const int wave = tid >> 6, lane = tid & 63;
  const int wm = wave >> 1, wn = wave & 1;
  const int lr = lane & 15, lk = lane >> 4;
  const int m0 = blockIdx.y * BM, n0 = blockIdx.x * BN;
  constexpr int WMt = BM / 2, WNt = BN / 2;
  constexpr int CPR = BK / 8;  // 16B chunks per row
  constexpr int CHA = BM * CPR, CHB = BN * CPR;

  floatx4 acc[TM][TN];
#pragma unroll
  for (int i = 0; i < TM; i++)
#pragma unroll
    for (int j = 0; j < TN; j++) acc[i][j] = (floatx4){0.f, 0.f, 0.f, 0.f};

  for (int k0 = 0; k0 < K; k0 += BK) {
    for (int c = tid; c < CHA; c += 256) {
      int r = c / CPR, q = c % CPR;
      *(uint4*)&As[r * BK + q * 8] =
          *(const uint4*)&A[(size_t)(m0 + r) * K + k0 + q * 8];
    }
    for (int c = tid; c < CHB; c += 256) {
      int r = c / CPR, q = c % CPR;
      *(uint4*)&Bs[r * BK + q * 8] =
          *(const uint4*)&W[(size_t)(n0 + r) * K + k0 + q * 8];
    }
    __syncthreads();
#pragma unroll
    for (int kk = 0; kk < BK; kk += 32) {
      short8 af[TM], bw[TN];
#pragma unroll
      for (int i = 0; i < TM; i++)
        af[i] = *(const short8*)&As[(wm * WMt + i * 16 + lr) * BK + kk + lk * 8];
#pragma unroll
      for (int j = 0; j < TN; j++)
        bw[j] = *(const short8*)&Bs[(wn * WNt + j * 16 + lr) * BK + kk + lk * 8];
#pragma unroll
      for (int i = 0; i < TM; i++)
#pragma unroll
        for (int j = 0; j < TN; j++)
          acc[i][j] = __builtin_amdgcn_mfma_f32_16x16x32_bf16(
              af[i], bw[j], acc[i][j], 0, 0, 0);
    }
    __syncthreads();
  }

  // C/D layout (m89-verified): col = lane&15, row = (lane>>4)*4 + reg
#pragma unroll
  for (int i = 0; i < TM; i++) {
#pragma unroll
    for (int j = 0; j < TN; j++) {
#pragma unroll
      for (int r = 0; r < 4; r++) {
        int m = m0 + wm * WMt + i * 16 + lk * 4 + r;
        int n = n0 + wn * WNt + j * 16 + lr;
        float v = acc[i][j][r];
        if (EPI == 0) {
          Cf[(size_t)m * N + n] = v;
        } else {
          v += bias[n];
          Cb[(size_t)m * N + n] = f2bf(elu1(v));
        }
      }
    }
  }
}

// ---------------- gate logits + softmax (one wave per sample) ----------------
__global__ __launch_bounds__(64) void gate_kernel(
    const unsigned short* __restrict__ G1,  // [B,H] bf16
    const float* __restrict__ gw2,          // [E,H]
    const float* __restrict__ gb2,          // [E]
    float* __restrict__ g) {                // [B,E]
  int b = blockIdx.x;
  int lane = threadIdx.x;
  float xv[8];
#pragma unroll
  for (int t = 0; t < 8; t++) xv[t] = bf2f(G1[(size_t)b * Hq + t * 64 + lane]);
  float le[Eq];
#pragma unroll
  for (int e = 0; e < Eq; e++) {
    float p = 0.f;
#pragma unroll
    for (int t = 0; t < 8; t++)
      p += xv[t] * gw2[(size_t)e * Hq + t * 64 + lane];
#pragma unroll
    for (int o = 32; o > 0; o >>= 1) p += __shfl_xor(p, o);
    le[e] = p + gb2[e];
  }
  float m = le[0];
#pragma unroll
  for (int e = 1; e < Eq; e++) m = fmaxf(m, le[e]);
  float s = 0.f;
#pragma unroll
  for (int e = 0; e < Eq; e++) {
    le[e] = __expf(le[e] - m);
    s += le[e];
  }
  float inv = 1.f / s;
  if (lane == 0) {
#pragma unroll
    for (int e = 0; e < Eq; e++) g[(size_t)b * Eq + e] = le[e] * inv;
  }
}

// ------------- gate-weighted expert combine (+ optional ELU/bf16) -----------
template <int ACT>
__global__ __launch_bounds__(256) void combine_kernel(
    const float* __restrict__ Y,     // [B, E*H]
    const float* __restrict__ g,     // [B, E]
    const float* __restrict__ beta,  // [E*H]
    unsigned short* __restrict__ outb, float* __restrict__ outf) {
  int idx = blockIdx.x * 256 + threadIdx.x;  // b*H + h
  int b = idx >> 9, h = idx & 511;           // H == 512
  const float* gb = g + (size_t)b * Eq;
  const float* y = Y + (size_t)b * Eq * Hq;
  float s = 0.f;
#pragma unroll
  for (int e = 0; e < Eq; e++)
    s += gb[e] * (y[e * Hq + h] + beta[e * Hq + h]);
  if (ACT)
    outb[idx] = f2bf(elu1(s));
  else
    outf[idx] = s;
}

extern "C" void kernel_launch(void* const* d_in, const int* in_sizes, int n_in,
                              void* d_out, int out_size, void* d_ws,
                              size_t ws_size, hipStream_t stream) {
  const float* x = (const float*)d_in[0];
  const float* gw0 = (const float*)d_in[1];
  const float* gb0 = (const float*)d_in[2];
  const float* gw1 = (const float*)d_in[3];
  const float* gb1 = (const float*)d_in[4];
  const float* gw2 = (const float*)d_in[5];
  const float* gb2 = (const float*)d_in[6];
  const float* alpha0 = (const float*)d_in[7];
  const float* beta0 = (const float*)d_in[8];
  const float* alpha1 = (const float*)d_in[9];
  const float* beta1 = (const float*)d_in[10];
  const float* alpha2 = (const float*)d_in[11];
  const float* beta2 = (const float*)d_in[12];
  float* out = (float*)d_out;

  char* ws = (char*)d_ws;
  auto alloc = [&](size_t bytes) {
    char* p = ws;
    ws += (bytes + 255) & ~(size_t)255;
    return p;
  };
  unsigned short* xb = (unsigned short*)alloc((size_t)Bq * Fq * 2);
  unsigned short* gw0b = (unsigned short*)alloc((size_t)Hq * Fq * 2);
  unsigned short* gw1b = (unsigned short*)alloc((size_t)Hq * Hq * 2);
  unsigned short* a0b = (unsigned short*)alloc((size_t)Eq * Hq * Fq * 2);
  unsigned short* a1b = (unsigned short*)alloc((size_t)Eq * Hq * Hq * 2);
  unsigned short* a2b = (unsigned short*)alloc((size_t)Eq * Oq * Hq * 2);
  unsigned short* G0b = (unsigned short*)alloc((size_t)Bq * Hq * 2);
  unsigned short* G1b = (unsigned short*)alloc((size_t)Bq * Hq * 2);
  unsigned short* H1b = (unsigned short*)alloc((size_t)Bq * Hq * 2);
  unsigned short* H2b = (unsigned short*)alloc((size_t)Bq * Hq * 2);
  float* gates = (float*)alloc((size_t)Bq * Eq * 4);
  float* Y = (float*)alloc((size_t)Bq * Eq * Hq * 4);

  // 1) converts: x/gw0/gw1 (262144 elems each), alpha banks (2097152 each)
  cvt3_kernel<<<768, 256, 0, stream>>>(x, gw0, gw1, xb, gw0b, gw1b,
                                       (Bq * Fq) / 4);
  cvt3_kernel<<<6144, 256, 0, stream>>>(alpha0, alpha1, alpha2, a0b, a1b, a2b,
                                        (Eq * Hq * Fq) / 4);

  // 2) gating MLP: two 512x512x512 GEMMs with bias+ELU epilogue
  dim3 gg(Hq / 64, Bq / 64);
  gemm_bt<64, 64, 64, 2, 2, 1><<<gg, 256, 0, stream>>>(
      xb, gw0b, gb0, nullptr, G0b, Bq, Hq, Fq);
  gemm_bt<64, 64, 64, 2, 2, 1><<<gg, 256, 0, stream>>>(
      G0b, gw1b, gb1, nullptr, G1b, Bq, Hq, Hq);

  // 3) gate logits + softmax
  gate_kernel<<<Bq, 64, 0, stream>>>(G1b, gw2, gb2, gates);

  // 4) experts: Y = act_in @ alpha_flat^T (M=512,N=4096,K=512), then combine
  dim3 ge((Eq * Hq) / 128, Bq / 128);
  gemm_bt<128, 128, 64, 4, 4, 0><<<ge, 256, 0, stream>>>(
      xb, a0b, nullptr, Y, nullptr, Bq, Eq * Hq, Fq);
  combine_kernel<1><<<(Bq * Hq) / 256, 256, 0, stream>>>(Y, gates, beta0, H1b,
                                                         nullptr);
  gemm_bt<128, 128, 64, 4, 4, 0><<<ge, 256, 0, stream>>>(
      H1b, a1b, nullptr, Y, nullptr, Bq, Eq * Hq, Hq);
  combine_kernel<1><<<(Bq * Hq) / 256, 256, 0, stream>>>(Y, gates, beta1, H2b,
                                                         nullptr);
  gemm_bt<128, 128, 64, 4, 4, 0><<<ge, 256, 0, stream>>>(
      H2b, a2b, nullptr, Y, nullptr, Bq, Eq * Oq, Hq);
  combine_kernel<0><<<(Bq * Oq) / 256, 256, 0, stream>>>(Y, gates, beta2,
                                                         nullptr, out);
}

// Round 2
// 162.252 us; speedup vs baseline: 1.3702x; 1.3702x over previous
//
#include <hip/hip_runtime.h>
#include <hip/hip_bf16.h>
#include <math.h>

// Problem constants (B,F,H,E,O) = (512,512,512,8,512)
enum { Bq = 512, Fq = 512, Hq = 512, Eq = 8, Oq = 512 };

typedef __attribute__((ext_vector_type(8))) short short8;
typedef __attribute__((ext_vector_type(4))) float floatx4;

static __device__ __forceinline__ unsigned short f2bf(float f) {
  unsigned u = __float_as_uint(f);
  u += 0x7fffu + ((u >> 16) & 1u);
  return (unsigned short)(u >> 16);
}
static __device__ __forceinline__ float bf2f(unsigned short h) {
  return __uint_as_float(((unsigned)h) << 16);
}
static __device__ __forceinline__ float elu1(float v) {
  return v > 0.f ? v : (__expf(v) - 1.f);
}

// async global->LDS 16B copy (wave-uniform LDS base + lane*16 scatter)
typedef __attribute__((address_space(1))) const unsigned int gu32;
typedef __attribute__((address_space(3))) unsigned int lu32;
static __device__ __forceinline__ void gld16(const unsigned short* g,
                                             unsigned short* l) {
  __builtin_amdgcn_global_load_lds((gu32*)g, (lu32*)l, 16, 0, 0);
}

// ---------- fp32 -> bf16 convert, 3 big (alpha) + 3 small segments ----------
__global__ __launch_bounds__(256) void cvt6_kernel(
    const float* __restrict__ b0, const float* __restrict__ b1,
    const float* __restrict__ b2, unsigned short* __restrict__ db0,
    unsigned short* __restrict__ db1, unsigned short* __restrict__ db2,
    const float* __restrict__ s0, const float* __restrict__ s1,
    const float* __restrict__ s2, unsigned short* __restrict__ ds0,
    unsigned short* __restrict__ ds1, unsigned short* __restrict__ ds2,
    int nb, int ns) {
  int i = blockIdx.x * 256 + threadIdx.x;
  const float4* s;
  unsigned short* d;
  int j;
  if (i < 3 * nb) {
    int seg = i / nb;
    j = i - seg * nb;
    s = (seg == 0) ? (const float4*)b0
      : (seg == 1) ? (const float4*)b1 : (const float4*)b2;
    d = (seg == 0) ? db0 : (seg == 1) ? db1 : db2;
  } else {
    int k = i - 3 * nb;
    if (k >= 3 * ns) return;
    int seg = k / ns;
    j = k - seg * ns;
    s = (seg == 0) ? (const float4*)s0
      : (seg == 1) ? (const float4*)s1 : (const float4*)s2;
    d = (seg == 0) ? ds0 : (seg == 1) ? ds1 : ds2;
  }
  float4 v = s[j];
  ushort4 o;
  o.x = f2bf(v.x); o.y = f2bf(v.y); o.z = f2bf(v.z); o.w = f2bf(v.w);
  *(ushort4*)(d + 4 * (size_t)j) = o;
}

// ---------------- bf16 MFMA GEMM: C[M,N] = A[M,K] @ W[N,K]^T ----------------
// A, W row-major K-contiguous. 256 threads = 4 waves in 2x2.
// KS-way split-K over blockIdx.z; EPI==0 stores fp32 partial to
// Cf + z*M*N, EPI==1 (KS must be 1): +bias, ELU, store bf16 to Cb.
template <int BM, int BN, int BK, int TM, int TN, int EPI, int KS>
__global__ __launch_bounds__(256) void gemm_bt(
    const unsigned short* __restrict__ A, const unsigned short* __restrict__ W,
    const float* __restrict__ bias, float* __restrict__ Cf,
    unsigned short* __restrict__ Cb, int M, int N, int K) {
  __shared__ unsigned short As[BM * BK];
  __shared__ unsigned short Bs[BN * BK];
  const int tid = threadIdx.x;
  const int wave = tid >> 6, lane = tid & 63;
  const int wm = wave >> 1, wn = wave & 1;
  const int lr = lane & 15, lk = lane >> 4;
  const int m0 = blockIdx.y * BM, n0 = blockIdx.x * BN;
  const int Ksl = K / KS;
  const int kbeg = blockIdx.z * Ksl, kend = kbeg + Ksl;
  constexpr int WMt = BM / 2, WNt = BN / 2;
  constexpr int CPR = BK / 8;  // 16B chunks per row
  constexpr int CHA = BM * CPR, CHB = BN * CPR;

  floatx4 acc[TM][TN];
#pragma unroll
  for (int i = 0; i < TM; i++)
#pragma unroll
    for (int j = 0; j < TN; j++) acc[i][j] = (floatx4){0.f, 0.f, 0.f, 0.f};

  for (int k0 = kbeg; k0 < kend; k0 += BK) {
    // async 16B global->LDS staging; chunk c lives at LDS elem offset c*8,
    // wave-uniform base (c&~63)*8, lane scatters +lane*16B.
#pragma unroll
    for (int c = tid; c < CHA; c += 256) {
      int r = c / CPR, q = c % CPR;
      gld16(&A[(size_t)(m0 + r) * K + k0 + q * 8], &As[(c & ~63) * 8]);
    }
#pragma unroll
    for (int c = tid; c < CHB; c += 256) {
      int r = c / CPR, q = c % CPR;
      gld16(&W[(size_t)(n0 + r) * K + k0 + q * 8], &Bs[(c & ~63) * 8]);
    }
    __syncthreads();
#pragma unroll
    for (int kk = 0; kk < BK; kk += 32) {
      short8 af[TM], bw[TN];
#pragma unroll
      for (int i = 0; i < TM; i++)
        af[i] = *(const short8*)&As[(wm * WMt + i * 16 + lr) * BK + kk + lk * 8];
#pragma unroll
      for (int j = 0; j < TN; j++)
        bw[j] = *(const short8*)&Bs[(wn * WNt + j * 16 + lr) * BK + kk + lk * 8];
#pragma unroll
      for (int i = 0; i < TM; i++)
#pragma unroll
        for (int j = 0; j < TN; j++)
          acc[i][j] = __builtin_amdgcn_mfma_f32_16x16x32_bf16(
              af[i], bw[j], acc[i][j], 0, 0, 0);
    }
    __syncthreads();
  }

  float* Cfo = Cf + (size_t)blockIdx.z * M * N;
  // C/D layout (m89-verified): col = lane&15, row = (lane>>4)*4 + reg
#pragma unroll
  for (int i = 0; i < TM; i++) {
#pragma unroll
    for (int j = 0; j < TN; j++) {
#pragma unroll
      for (int r = 0; r < 4; r++) {
        int m = m0 + wm * WMt + i * 16 + lk * 4 + r;
        int n = n0 + wn * WNt + j * 16 + lr;
        float v = acc[i][j][r];
        if (EPI == 0) {
          Cfo[(size_t)m * N + n] = v;
        } else {
          v += bias[n];
          Cb[(size_t)m * N + n] = f2bf(elu1(v));
        }
      }
    }
  }
}

// ---------------- gate logits + softmax (one wave per sample) ----------------
__global__ __launch_bounds__(64) void gate_kernel(
    const unsigned short* __restrict__ G1,  // [B,H] bf16
    const float* __restrict__ gw2,          // [E,H]
    const float* __restrict__ gb2,          // [E]
    float* __restrict__ g) {                // [B,E]
  int b = blockIdx.x;
  int lane = threadIdx.x;
  float xv[8];
#pragma unroll
  for (int t = 0; t < 8; t++) xv[t] = bf2f(G1[(size_t)b * Hq + t * 64 + lane]);
  float le[Eq];
#pragma unroll
  for (int e = 0; e < Eq; e++) {
    float p = 0.f;
#pragma unroll
    for (int t = 0; t < 8; t++)
      p += xv[t] * gw2[(size_t)e * Hq + t * 64 + lane];
#pragma unroll
    for (int o = 32; o > 0; o >>= 1) p += __shfl_xor(p, o);
    le[e] = p + gb2[e];
  }
  float m = le[0];
#pragma unroll
  for (int e = 1; e < Eq; e++) m = fmaxf(m, le[e]);
  float s = 0.f;
#pragma unroll
  for (int e = 0; e < Eq; e++) {
    le[e] = __expf(le[e] - m);
    s += le[e];
  }
  float inv = 1.f / s;
  if (lane == 0) {
#pragma unroll
    for (int e = 0; e < Eq; e++) g[(size_t)b * Eq + e] = le[e] * inv;
  }
}

// ------ gate-weighted expert combine over KS partials (+opt ELU/bf16) -------
template <int ACT, int KS>
__global__ __launch_bounds__(256) void combine_kernel(
    const float* __restrict__ Y,     // [KS][B][E*H]
    const float* __restrict__ g,     // [B, E]
    const float* __restrict__ beta,  // [E*H]
    unsigned short* __restrict__ outb, float* __restrict__ outf) {
  int idx = blockIdx.x * 256 + threadIdx.x;  // b*H + h
  int b = idx >> 9, h = idx & 511;           // H == 512
  const float* gb = g + (size_t)b * Eq;
  const float* y = Y + (size_t)b * Eq * Hq;
  float s = 0.f;
#pragma unroll
  for (int e = 0; e < Eq; e++) {
    float ye = beta[e * Hq + h];
#pragma unroll
    for (int p = 0; p < KS; p++)
      ye += y[(size_t)p * Bq * Eq * Hq + e * Hq + h];
    s += gb[e] * ye;
  }
  if (ACT)
    outb[idx] = f2bf(elu1(s));
  else
    outf[idx] = s;
}

extern "C" void kernel_launch(void* const* d_in, const int* in_sizes, int n_in,
                              void* d_out, int out_size, void* d_ws,
                              size_t ws_size, hipStream_t stream) {
  const float* x = (const float*)d_in[0];
  const float* gw0 = (const float*)d_in[1];
  const float* gb0 = (const float*)d_in[2];
  const float* gw1 = (const float*)d_in[3];
  const float* gb1 = (const float*)d_in[4];
  const float* gw2 = (const float*)d_in[5];
  const float* gb2 = (const float*)d_in[6];
  const float* alpha0 = (const float*)d_in[7];
  const float* beta0 = (const float*)d_in[8];
  const float* alpha1 = (const float*)d_in[9];
  const float* beta1 = (const float*)d_in[10];
  const float* alpha2 = (const float*)d_in[11];
  const float* beta2 = (const float*)d_in[12];
  float* out = (float*)d_out;

  char* ws = (char*)d_ws;
  auto alloc = [&](size_t bytes) {
    char* p = ws;
    ws += (bytes + 255) & ~(size_t)255;
    return p;
  };
  unsigned short* xb = (unsigned short*)alloc((size_t)Bq * Fq * 2);
  unsigned short* gw0b = (unsigned short*)alloc((size_t)Hq * Fq * 2);
  unsigned short* gw1b = (unsigned short*)alloc((size_t)Hq * Hq * 2);
  unsigned short* a0b = (unsigned short*)alloc((size_t)Eq * Hq * Fq * 2);
  unsigned short* a1b = (unsigned short*)alloc((size_t)Eq * Hq * Hq * 2);
  unsigned short* a2b = (unsigned short*)alloc((size_t)Eq * Oq * Hq * 2);
  unsigned short* G0b = (unsigned short*)alloc((size_t)Bq * Hq * 2);
  unsigned short* G1b = (unsigned short*)alloc((size_t)Bq * Hq * 2);
  unsigned short* H1b = (unsigned short*)alloc((size_t)Bq * Hq * 2);
  unsigned short* H2b = (unsigned short*)alloc((size_t)Bq * Hq * 2);
  float* gates = (float*)alloc((size_t)Bq * Eq * 4);
  float* Y = (float*)alloc((size_t)2 * Bq * Eq * Hq * 4);  // 2 split-K partials

  // 1) all fp32->bf16 converts in one launch
  {
    int nb = (Eq * Hq * Fq) / 4, ns = (Bq * Fq) / 4;
    int total = 3 * nb + 3 * ns;
    cvt6_kernel<<<(total + 255) / 256, 256, 0, stream>>>(
        alpha0, alpha1, alpha2, a0b, a1b, a2b, x, gw0, gw1, xb, gw0b, gw1b,
        nb, ns);
  }

  // 2) gating MLP: 32x64 tiles -> 128 blocks each
  dim3 gg(Hq / 64, Bq / 32);
  gemm_bt<32, 64, 64, 1, 2, 1, 1><<<gg, 256, 0, stream>>>(
      xb, gw0b, gb0, nullptr, G0b, Bq, Hq, Fq);
  gemm_bt<32, 64, 64, 1, 2, 1, 1><<<gg, 256, 0, stream>>>(
      G0b, gw1b, gb1, nullptr, G1b, Bq, Hq, Hq);

  // 3) gate logits + softmax
  gate_kernel<<<Bq, 64, 0, stream>>>(G1b, gw2, gb2, gates);

  // 4) experts: split-K=2 -> 256 blocks; combine fuses the K-reduction
  dim3 ge((Eq * Hq) / 128, Bq / 128, 2);
  gemm_bt<128, 128, 64, 4, 4, 0, 2><<<ge, 256, 0, stream>>>(
      xb, a0b, nullptr, Y, nullptr, Bq, Eq * Hq, Fq);
  combine_kernel<1, 2><<<(Bq * Hq) / 256, 256, 0, stream>>>(Y, gates, beta0,
                                                            H1b, nullptr);
  gemm_bt<128, 128, 64, 4, 4, 0, 2><<<ge, 256, 0, stream>>>(
      H1b, a1b, nullptr, Y, nullptr, Bq, Eq * Hq, Hq);
  combine_kernel<1, 2><<<(Bq * Hq) / 256, 256, 0, stream>>>(Y, gates, beta1,
                                                            H2b, nullptr);
  gemm_bt<128, 128, 64, 4, 4, 0, 2><<<ge, 256, 0, stream>>>(
      H2b, a2b, nullptr, Y, nullptr, Bq, Eq * Oq, Hq);
  combine_kernel<0, 2><<<(Bq * Oq) / 256, 256, 0, stream>>>(Y, gates, beta2,
                                                            nullptr, out);
}